// Round 1
// baseline (825.232 us; speedup 1.0000x reference)
//
#include <hip/hip_runtime.h>
#include <stdint.h>

typedef __bf16 bf16;
typedef __bf16 bf16x8 __attribute__((ext_vector_type(8)));
typedef __bf16 bf16x4 __attribute__((ext_vector_type(4)));
typedef float f32x4 __attribute__((ext_vector_type(4)));

#define MFMA16(a, b, c) __builtin_amdgcn_mfma_f32_16x16x32_bf16(a, b, c, 0, 0, 0)

// ---------------------------------------------------------------------------
// Weight transpose + fp32->bf16 convert:  out[n][k] = (bf16) in[k][n]
// in: (512 x N) fp32 row-major, out: (N x 512) bf16 row-major
// ---------------------------------------------------------------------------
__global__ __launch_bounds__(256) void transpose_w(const float* __restrict__ in,
                                                   bf16* __restrict__ out, int N) {
  __shared__ float tile[32][33];
  const int n0 = blockIdx.x * 32, k0 = blockIdx.y * 32;
  const int tx = threadIdx.x, ty = threadIdx.y;
#pragma unroll
  for (int i = 0; i < 4; ++i)
    tile[ty * 4 + i][tx] = in[(size_t)(k0 + ty * 4 + i) * N + n0 + tx];
  __syncthreads();
#pragma unroll
  for (int i = 0; i < 4; ++i)
    out[(size_t)(n0 + ty * 4 + i) * 512 + k0 + tx] = (bf16)tile[tx][ty * 4 + i];
}

// ---------------------------------------------------------------------------
// LayerNorm: x (57344 x 512) fp32 -> h bf16, rows remapped into
// scale-contiguous blocks: [S: 16x512][M: 16x1024][L: 16x2048]
// one wave per row
// ---------------------------------------------------------------------------
__global__ __launch_bounds__(256) void ln_kernel(const float* __restrict__ x,
                                                 const float* __restrict__ gamma,
                                                 const float* __restrict__ beta,
                                                 bf16* __restrict__ h) {
  const int t = threadIdx.x, lane = t & 63, w = t >> 6;
  const int row = blockIdx.x * 4 + w;
  const float* xr = x + (size_t)row * 512 + lane * 8;
  float4 v0 = *(const float4*)xr;
  float4 v1 = *(const float4*)(xr + 4);
  float s = v0.x + v0.y + v0.z + v0.w + v1.x + v1.y + v1.z + v1.w;
  float q = v0.x * v0.x + v0.y * v0.y + v0.z * v0.z + v0.w * v0.w +
            v1.x * v1.x + v1.y * v1.y + v1.z * v1.z + v1.w * v1.w;
#pragma unroll
  for (int off = 1; off < 64; off <<= 1) {
    s += __shfl_xor(s, off);
    q += __shfl_xor(q, off);
  }
  const float mean = s * (1.0f / 512.0f);
  const float var = q * (1.0f / 512.0f) - mean * mean;
  const float rs = rsqrtf(var + 1e-5f);
  float4 g0 = *(const float4*)(gamma + lane * 8);
  float4 g1 = *(const float4*)(gamma + lane * 8 + 4);
  float4 b0 = *(const float4*)(beta + lane * 8);
  float4 b1 = *(const float4*)(beta + lane * 8 + 4);
  const int bb = row / 3584;
  const int sp = row - bb * 3584;
  size_t drow;
  if (sp < 512)
    drow = (size_t)bb * 512 + sp;
  else if (sp < 1536)
    drow = 8192 + (size_t)bb * 1024 + (sp - 512);
  else
    drow = 24576 + (size_t)bb * 2048 + (sp - 1536);
  bf16x8 ov = {(bf16)((v0.x - mean) * rs * g0.x + b0.x),
               (bf16)((v0.y - mean) * rs * g0.y + b0.y),
               (bf16)((v0.z - mean) * rs * g0.z + b0.z),
               (bf16)((v0.w - mean) * rs * g0.w + b0.w),
               (bf16)((v1.x - mean) * rs * g1.x + b1.x),
               (bf16)((v1.y - mean) * rs * g1.y + b1.y),
               (bf16)((v1.z - mean) * rs * g1.z + b1.z),
               (bf16)((v1.w - mean) * rs * g1.w + b1.w)};
  *(bf16x8*)(h + drow * 512 + lane * 8) = ov;
}

// ---------------------------------------------------------------------------
// QKV GEMM: C[M x 1536] = A[M x 512] * W[512 x 1536] + bias
// A row-major bf16, Bt = W^T (1536 x 512) bf16 row-major.
// Q,K (cols 0..1023) -> qk buffer (stride 1024) row-major bf16.
// V  (cols 1024..1535) -> vt transposed per batch: vt[b*512*L + d*L + kv].
// 128x128 tile, BK=64, 4 waves, XOR-swizzled LDS.
// ---------------------------------------------------------------------------
__global__ __launch_bounds__(256) void qkv_gemm(const bf16* __restrict__ A,
                                                const bf16* __restrict__ Bt,
                                                const float* __restrict__ bias,
                                                bf16* __restrict__ qk,
                                                bf16* __restrict__ vt, int l2L) {
  __shared__ bf16 As[128 * 64];
  __shared__ bf16 Bs[128 * 64];
  const int t = threadIdx.x, lane = t & 63, w = t >> 6;
  const int wm = w >> 1, wn = w & 1;
  const int m0 = blockIdx.x * 128, n0 = blockIdx.y * 128;
  const int L = 1 << l2L;

  f32x4 acc[4][4];
#pragma unroll
  for (int i = 0; i < 4; ++i)
#pragma unroll
    for (int j = 0; j < 4; ++j) acc[i][j] = (f32x4)0.0f;

  const int srow = t >> 3;  // 0..31
  const int sc = t & 7;     // 16B chunk in row

  for (int kt = 0; kt < 8; ++kt) {
    const int k0 = kt * 64;
#pragma unroll
    for (int i = 0; i < 4; ++i) {
      const int row = i * 32 + srow;
      uint4 va = *(const uint4*)(A + (size_t)(m0 + row) * 512 + k0 + sc * 8);
      uint4 vb = *(const uint4*)(Bt + (size_t)(n0 + row) * 512 + k0 + sc * 8);
      *(uint4*)((char*)As + row * 128 + ((sc ^ (row & 7)) << 4)) = va;
      *(uint4*)((char*)Bs + row * 128 + ((sc ^ (row & 7)) << 4)) = vb;
    }
    __syncthreads();
#pragma unroll
    for (int kk = 0; kk < 2; ++kk) {
      bf16x8 af[4], bfr[4];
#pragma unroll
      for (int mi = 0; mi < 4; ++mi) {
        const int r = wm * 64 + mi * 16 + (lane & 15);
        const int ch = kk * 4 + (lane >> 4);
        af[mi] = *(const bf16x8*)((const char*)As + r * 128 + ((ch ^ (r & 7)) << 4));
      }
#pragma unroll
      for (int ni = 0; ni < 4; ++ni) {
        const int r = wn * 64 + ni * 16 + (lane & 15);
        const int ch = kk * 4 + (lane >> 4);
        bfr[ni] = *(const bf16x8*)((const char*)Bs + r * 128 + ((ch ^ (r & 7)) << 4));
      }
#pragma unroll
      for (int mi = 0; mi < 4; ++mi)
#pragma unroll
        for (int ni = 0; ni < 4; ++ni)
          acc[mi][ni] = MFMA16(af[mi], bfr[ni], acc[mi][ni]);
    }
    __syncthreads();
  }

  const bool isV = (n0 >= 1024);
#pragma unroll
  for (int ni = 0; ni < 4; ++ni) {
    const int col = n0 + wn * 64 + ni * 16 + (lane & 15);
    const float bv = bias[col];
#pragma unroll
    for (int mi = 0; mi < 4; ++mi) {
      const int rb = m0 + wm * 64 + mi * 16 + ((lane >> 4) << 2);
      if (!isV) {
#pragma unroll
        for (int r = 0; r < 4; ++r)
          qk[(size_t)(rb + r) * 1024 + col] = (bf16)(acc[mi][ni][r] + bv);
      } else {
        const int d = col - 1024;
        const int bi = rb >> l2L;
        const int kv = rb & (L - 1);
        bf16x4 pk = {(bf16)(acc[mi][ni][0] + bv), (bf16)(acc[mi][ni][1] + bv),
                     (bf16)(acc[mi][ni][2] + bv), (bf16)(acc[mi][ni][3] + bv)};
        *(bf16x4*)(vt + ((size_t)bi * 512 + d) * L + kv) = pk;
      }
    }
  }
}

// ---------------------------------------------------------------------------
// Flash attention, one scale. grid = 16 * (L/64), block = 512 (8 waves).
// bid: b = bid&15, qtile = bid>>4. Q tile 64 rows LDS-resident (swizzled).
// Computes S^T = K*Q^T (K as A-frags direct from global/L2),
// in-register online softmax with cross-wave LDS exchange,
// O^T = V^T * P^T (V^T frags direct from global/L2, P from LDS).
// Writes O (rows x 512 bf16) into o (the h buffer region).
// ---------------------------------------------------------------------------
__global__ __launch_bounds__(512) void attn(const bf16* __restrict__ qkbuf,
                                            const bf16* __restrict__ vt,
                                            bf16* __restrict__ o, int L,
                                            float scale) {
  __shared__ bf16 Qs[64 * 512];   // 64KB, swizzled
  __shared__ bf16 Ps[64 * 264];   // P, row stride 264 (pad)
  __shared__ float cmax[8][64];
  __shared__ float csum[8][64];
  __shared__ float mrow[64];
  __shared__ float lrow[64];
  __shared__ float frow[64];

  const int t = threadIdx.x, lane = t & 63, w = t >> 6;
  const int b = blockIdx.x & 15, qt = blockIdx.x >> 4;

  const bf16* qbase = qkbuf + ((size_t)b * L + qt * 64) * 1024;
  const bf16* kbase = qkbuf + (size_t)b * L * 1024 + 512;
  const bf16* vbase = vt + (size_t)b * 512 * L;

  // stage Q (swizzled), one row (1KB) per wave-instruction
#pragma unroll
  for (int i = 0; i < 8; ++i) {
    const int row = i * 8 + w;
    uint4 v = *(const uint4*)(qbase + (size_t)row * 1024 + lane * 8);
    *(uint4*)((char*)Qs + row * 1024 + ((lane ^ (row & 7)) << 4)) = v;
  }
  if (t < 64) {
    mrow[t] = -INFINITY;
    lrow[t] = 0.0f;
  }
  __syncthreads();

  f32x4 oacc[4][4];  // [dt][qg] : O^T tile, d = w*64+dt*16+(l>>4)*4+r, q = qg*16+(l&15)
#pragma unroll
  for (int i = 0; i < 4; ++i)
#pragma unroll
    for (int j = 0; j < 4; ++j) oacc[i][j] = (f32x4)0.0f;

  const float L2E = 1.44269504088896f;
  const int nmega = L >> 8;
  for (int mg = 0; mg < nmega; ++mg) {
    const int kvw = mg * 256 + w * 32;  // this wave's kv slice
    f32x4 st[2][4];                     // S^T: [kt][qg]
#pragma unroll
    for (int i = 0; i < 2; ++i)
#pragma unroll
      for (int j = 0; j < 4; ++j) st[i][j] = (f32x4)0.0f;

    const bf16* kr = kbase + (size_t)kvw * 1024;
    for (int ks = 0; ks < 16; ++ks) {
      bf16x8 af[2], bq[4];
#pragma unroll
      for (int kt = 0; kt < 2; ++kt)
        af[kt] = *(const bf16x8*)(kr + (size_t)(kt * 16 + (lane & 15)) * 1024 +
                                  ks * 32 + ((lane >> 4) << 3));
#pragma unroll
      for (int qg = 0; qg < 4; ++qg) {
        const int qr = qg * 16 + (lane & 15);
        const int ch = ks * 4 + (lane >> 4);
        bq[qg] = *(const bf16x8*)((const char*)Qs + qr * 1024 +
                                  ((ch ^ (qr & 7)) << 4));
      }
#pragma unroll
      for (int kt = 0; kt < 2; ++kt)
#pragma unroll
        for (int qg = 0; qg < 4; ++qg)
          st[kt][qg] = MFMA16(af[kt], bq[qg], st[kt][qg]);
    }
    // scale scores
#pragma unroll
    for (int kt = 0; kt < 2; ++kt)
#pragma unroll
      for (int qg = 0; qg < 4; ++qg) st[kt][qg] *= scale;

    // per-q (column) max of this wave's kv slice
#pragma unroll
    for (int qg = 0; qg < 4; ++qg) {
      float vm = -INFINITY;
#pragma unroll
      for (int kt = 0; kt < 2; ++kt)
#pragma unroll
        for (int r = 0; r < 4; ++r) vm = fmaxf(vm, st[kt][qg][r]);
      vm = fmaxf(vm, __shfl_xor(vm, 16));
      vm = fmaxf(vm, __shfl_xor(vm, 32));
      if (lane < 16) cmax[w][qg * 16 + lane] = vm;
    }
    __syncthreads();  // B1
    if (t < 64) {
      const float mo = mrow[t];
      float mn = mo;
#pragma unroll
      for (int j = 0; j < 8; ++j) mn = fmaxf(mn, cmax[j][t]);
      frow[t] = exp2f((mo - mn) * L2E);
      mrow[t] = mn;
    }
    __syncthreads();  // B2
#pragma unroll
    for (int qg = 0; qg < 4; ++qg) {
      const float mq = mrow[qg * 16 + (lane & 15)] * L2E;
      const float fq = frow[qg * 16 + (lane & 15)];
      float ssum = 0.0f;
#pragma unroll
      for (int kt = 0; kt < 2; ++kt) {
        const float p0 = exp2f(st[kt][qg][0] * L2E - mq);
        const float p1 = exp2f(st[kt][qg][1] * L2E - mq);
        const float p2 = exp2f(st[kt][qg][2] * L2E - mq);
        const float p3 = exp2f(st[kt][qg][3] * L2E - mq);
        ssum += p0 + p1 + p2 + p3;
        bf16x4 pk = {(bf16)p0, (bf16)p1, (bf16)p2, (bf16)p3};
        const int q = qg * 16 + (lane & 15);
        const int kvl = w * 32 + kt * 16 + ((lane >> 4) << 2);
        *(bf16x4*)(Ps + (size_t)q * 264 + kvl) = pk;
      }
      ssum += __shfl_xor(ssum, 16);
      ssum += __shfl_xor(ssum, 32);
      if (lane < 16) csum[w][qg * 16 + lane] = ssum;
      // rescale O accumulator
#pragma unroll
      for (int dt = 0; dt < 4; ++dt) oacc[dt][qg] *= fq;
    }
    __syncthreads();  // B3
    if (t < 64) {
      float l = lrow[t] * frow[t];
#pragma unroll
      for (int j = 0; j < 8; ++j) l += csum[j][t];
      lrow[t] = l;
    }
    // PV: O^T += V^T * P^T over this mega-span (256 kv)
#pragma unroll
    for (int ks = 0; ks < 8; ++ks) {
      bf16x8 av[4], bp[4];
#pragma unroll
      for (int dt = 0; dt < 4; ++dt)
        av[dt] = *(const bf16x8*)(vbase +
                                  (size_t)(w * 64 + dt * 16 + (lane & 15)) * L +
                                  mg * 256 + ks * 32 + ((lane >> 4) << 3));
#pragma unroll
      for (int qg = 0; qg < 4; ++qg)
        bp[qg] = *(const bf16x8*)(Ps + (size_t)(qg * 16 + (lane & 15)) * 264 +
                                  ks * 32 + ((lane >> 4) << 3));
#pragma unroll
      for (int dt = 0; dt < 4; ++dt)
#pragma unroll
        for (int qg = 0; qg < 4; ++qg)
          oacc[dt][qg] = MFMA16(av[dt], bp[qg], oacc[dt][qg]);
    }
    // no barrier needed: next iter's first LDS writes (cmax) are gated by B1,
    // and Ps/stat writes are gated by B2 of the next iteration.
  }

  __syncthreads();
  if (t < 64) frow[t] = 1.0f / lrow[t];
  __syncthreads();
#pragma unroll
  for (int qg = 0; qg < 4; ++qg) {
    const float inv = frow[qg * 16 + (lane & 15)];
    const size_t orow = (size_t)b * L + qt * 64 + qg * 16 + (lane & 15);
#pragma unroll
    for (int dt = 0; dt < 4; ++dt) {
      bf16x4 pk = {(bf16)(oacc[dt][qg][0] * inv), (bf16)(oacc[dt][qg][1] * inv),
                   (bf16)(oacc[dt][qg][2] * inv), (bf16)(oacc[dt][qg][3] * inv)};
      *(bf16x4*)(o + orow * 512 + w * 64 + dt * 16 + ((lane >> 4) << 2)) = pk;
    }
  }
}

// ---------------------------------------------------------------------------
// Out projection: out[g] = O[row] * Wout + bout + x[g]   (fp32 output)
// A = O (57344 x 512 bf16, scale-concat layout), Bt = Wout^T (512x512 bf16)
// ---------------------------------------------------------------------------
__device__ __forceinline__ int row2g(int row) {
  if (row < 8192) return ((row >> 9) * 3584) + (row & 511);
  if (row < 24576) {
    const int r = row - 8192;
    return ((r >> 10) * 3584) + 512 + (r & 1023);
  }
  const int r = row - 24576;
  return ((r >> 11) * 3584) + 1536 + (r & 2047);
}

__global__ __launch_bounds__(256) void out_gemm(const bf16* __restrict__ A,
                                                const bf16* __restrict__ Bt,
                                                const float* __restrict__ bias,
                                                const float* __restrict__ x,
                                                float* __restrict__ out) {
  __shared__ bf16 As[128 * 64];
  __shared__ bf16 Bs[128 * 64];
  const int t = threadIdx.x, lane = t & 63, w = t >> 6;
  const int wm = w >> 1, wn = w & 1;
  const int m0 = blockIdx.x * 128, n0 = blockIdx.y * 128;

  f32x4 acc[4][4];
#pragma unroll
  for (int i = 0; i < 4; ++i)
#pragma unroll
    for (int j = 0; j < 4; ++j) acc[i][j] = (f32x4)0.0f;

  const int srow = t >> 3;
  const int sc = t & 7;

  for (int kt = 0; kt < 8; ++kt) {
    const int k0 = kt * 64;
#pragma unroll
    for (int i = 0; i < 4; ++i) {
      const int row = i * 32 + srow;
      uint4 va = *(const uint4*)(A + (size_t)(m0 + row) * 512 + k0 + sc * 8);
      uint4 vb = *(const uint4*)(Bt + (size_t)(n0 + row) * 512 + k0 + sc * 8);
      *(uint4*)((char*)As + row * 128 + ((sc ^ (row & 7)) << 4)) = va;
      *(uint4*)((char*)Bs + row * 128 + ((sc ^ (row & 7)) << 4)) = vb;
    }
    __syncthreads();
#pragma unroll
    for (int kk = 0; kk < 2; ++kk) {
      bf16x8 af[4], bfr[4];
#pragma unroll
      for (int mi = 0; mi < 4; ++mi) {
        const int r = wm * 64 + mi * 16 + (lane & 15);
        const int ch = kk * 4 + (lane >> 4);
        af[mi] = *(const bf16x8*)((const char*)As + r * 128 + ((ch ^ (r & 7)) << 4));
      }
#pragma unroll
      for (int ni = 0; ni < 4; ++ni) {
        const int r = wn * 64 + ni * 16 + (lane & 15);
        const int ch = kk * 4 + (lane >> 4);
        bfr[ni] = *(const bf16x8*)((const char*)Bs + r * 128 + ((ch ^ (r & 7)) << 4));
      }
#pragma unroll
      for (int mi = 0; mi < 4; ++mi)
#pragma unroll
        for (int ni = 0; ni < 4; ++ni)
          acc[mi][ni] = MFMA16(af[mi], bfr[ni], acc[mi][ni]);
    }
    __syncthreads();
  }

#pragma unroll
  for (int ni = 0; ni < 4; ++ni) {
    const int col = n0 + wn * 64 + ni * 16 + (lane & 15);
    const float bv = bias[col];
#pragma unroll
    for (int mi = 0; mi < 4; ++mi) {
      const int rb = m0 + wm * 64 + mi * 16 + ((lane >> 4) << 2);
#pragma unroll
      for (int r = 0; r < 4; ++r) {
        const int g = row2g(rb + r);
        const size_t idx = (size_t)g * 512 + col;
        out[idx] = acc[mi][ni][r] + bv + x[idx];
      }
    }
  }
}

// ---------------------------------------------------------------------------
extern "C" void kernel_launch(void* const* d_in, const int* in_sizes, int n_in,
                              void* d_out, int out_size, void* d_ws,
                              size_t ws_size, hipStream_t stream) {
  const float* x = (const float*)d_in[0];
  const float* gamma = (const float*)d_in[1];
  const float* beta = (const float*)d_in[2];
  const float* Wq_s = (const float*)d_in[3];
  const float* bq_s = (const float*)d_in[4];
  const float* Wq_m = (const float*)d_in[5];
  const float* bq_m = (const float*)d_in[6];
  const float* Wq_l = (const float*)d_in[7];
  const float* bq_l = (const float*)d_in[8];
  const float* Wout = (const float*)d_in[9];
  const float* bout = (const float*)d_in[10];
  float* out = (float*)d_out;

  char* ws = (char*)d_ws;
  bf16* h = (bf16*)(ws);                      // 57344 x 512  (58,720,256 B)
  bf16* qk = (bf16*)(ws + 58720256ull);       // 57344 x 1024 (117,440,512 B)
  bf16* vt = (bf16*)(ws + 176160768ull);      // 57344 x 512  (58,720,256 B)
  bf16* wt_s = (bf16*)(ws + 234881024ull);    // 1536 x 512 bf16
  bf16* wt_m = (bf16*)(ws + 236453888ull);
  bf16* wt_l = (bf16*)(ws + 238026752ull);
  bf16* wt_o = (bf16*)(ws + 239599616ull);    // 512 x 512 bf16

  dim3 tb(32, 8);
  transpose_w<<<dim3(48, 16), tb, 0, stream>>>(Wq_s, wt_s, 1536);
  transpose_w<<<dim3(48, 16), tb, 0, stream>>>(Wq_m, wt_m, 1536);
  transpose_w<<<dim3(48, 16), tb, 0, stream>>>(Wq_l, wt_l, 1536);
  transpose_w<<<dim3(16, 16), tb, 0, stream>>>(Wout, wt_o, 512);

  ln_kernel<<<14336, 256, 0, stream>>>(x, gamma, beta, h);

  qkv_gemm<<<dim3(64, 12), 256, 0, stream>>>(h, wt_s, bq_s, qk, vt, 9);
  qkv_gemm<<<dim3(128, 12), 256, 0, stream>>>(h + 8192ull * 512, wt_m, bq_m,
                                              qk + 8192ull * 1024,
                                              vt + 4194304ull, 10);
  qkv_gemm<<<dim3(256, 12), 256, 0, stream>>>(h + 24576ull * 512, wt_l, bq_l,
                                              qk + 24576ull * 1024,
                                              vt + 12582912ull, 11);

  const float scale = 0.04419417382415922f;  // 512^-0.5
  attn<<<128, 512, 0, stream>>>(qk, vt, h, 512, scale);
  attn<<<256, 512, 0, stream>>>(qk + 8192ull * 1024, vt + 4194304ull,
                                h + 8192ull * 512, 1024, scale);
  attn<<<512, 512, 0, stream>>>(qk + 24576ull * 1024, vt + 12582912ull,
                                h + 24576ull * 512, 2048, scale);

  out_gemm<<<dim3(448, 4), 256, 0, stream>>>(h, wt_o, bout, x, out);
}